// Round 1
// baseline (29.819 us; speedup 1.0000x reference)
//
#include <hip/hip_runtime.h>

// Gaussian cross-attention: out[b,m,:] = sum_k w[b,m,k] * Q[b,k,:]
// w computed inline from segment_len (Gaussian pdf, min-max normalized per row).
// Memory-bound: 128 MiB output write dominates; Q (1.25 MiB) lives in L2/L3.

#define K_SUP 5

__global__ __launch_bounds__(256)
void gauss_xattn_kernel(const int* __restrict__ seg,
                        const float* __restrict__ Q,
                        float* __restrict__ out,
                        int M, int D) {
    const int bm = blockIdx.x;
    const int m = bm % M;
    const int b = bm / M;
    const int n = seg[b];

    float w[K_SUP];
    bool zero_row;
    if (n == 1) {
        // reference special case: frame[:1] = 1.0, rest zeros
        zero_row = (m != 0);
        #pragma unroll
        for (int k = 0; k < K_SUP; ++k) w[k] = 1.0f;
    } else if (m >= n) {
        zero_row = true;
        #pragma unroll
        for (int k = 0; k < K_SUP; ++k) w[k] = 0.0f;
    } else {
        zero_row = false;
        const float mu = (float)m * 4.0f / (float)(n - 1);
        float l[K_SUP];
        #pragma unroll
        for (int k = 0; k < K_SUP; ++k) {
            const float z = ((float)k - mu) * (1.0f / 2.5f);
            l[k] = __expf(-0.5f * z * z);
        }
        const float lmin = fminf(fminf(fminf(l[0], l[1]), fminf(l[2], l[3])), l[4]);
        const float lmax = fmaxf(fmaxf(fmaxf(l[0], l[1]), fmaxf(l[2], l[3])), l[4]);
        const float inv = 1.0f / (lmax - lmin);
        #pragma unroll
        for (int k = 0; k < K_SUP; ++k) w[k] = (l[k] - lmin) * inv;
    }

    const float* __restrict__ Qb = Q + (size_t)b * K_SUP * D;
    float* __restrict__ orow = out + (size_t)bm * D;

    for (int d = threadIdx.x * 4; d < D; d += blockDim.x * 4) {
        float4 o;
        if (zero_row) {
            o = make_float4(0.0f, 0.0f, 0.0f, 0.0f);
        } else {
            float4 acc = make_float4(0.0f, 0.0f, 0.0f, 0.0f);
            #pragma unroll
            for (int k = 0; k < K_SUP; ++k) {
                const float4 q = *reinterpret_cast<const float4*>(Qb + (size_t)k * D + d);
                acc.x += w[k] * q.x;
                acc.y += w[k] * q.y;
                acc.z += w[k] * q.z;
                acc.w += w[k] * q.w;
            }
            o = acc;
        }
        *reinterpret_cast<float4*>(orow + d) = o;
    }
}

extern "C" void kernel_launch(void* const* d_in, const int* in_sizes, int n_in,
                              void* d_out, int out_size, void* d_ws, size_t ws_size,
                              hipStream_t stream) {
    const int*   seg = (const int*)d_in[0];
    const float* Q   = (const float*)d_in[2];
    float*       out = (float*)d_out;

    const int B = in_sizes[0];
    const int D = in_sizes[2] / (B * K_SUP);   // 1024
    const int M = out_size / (B * D);          // 512

    dim3 grid(B * M);
    gauss_xattn_kernel<<<grid, 256, 0, stream>>>(seg, Q, out, M, D);
}